// Round 1
// baseline (1574.976 us; speedup 1.0000x reference)
//
#include <hip/hip_runtime.h>
#include <hip/hip_bf16.h>
#include <cstdint>
#include <cstddef>

#define EN 320000
#define NN 10000

typedef __bf16 bf16_t;
typedef __bf16 bf16x8 __attribute__((ext_vector_type(8)));
typedef float f32x4 __attribute__((ext_vector_type(4)));
typedef unsigned short u16x8 __attribute__((ext_vector_type(8)));

__device__ __forceinline__ unsigned short f2b(float x) {
  bf16_t h = (bf16_t)x;
  return __builtin_bit_cast(unsigned short, h);
}
__device__ __forceinline__ float gelu_f(float x) {
  return 0.5f * x * (1.0f + erff(x * 0.70710678118654752f));
}
__device__ __forceinline__ void async_cp16(const void* gp, void* lp) {
  __builtin_amdgcn_global_load_lds((__attribute__((address_space(1))) void*)gp,
                                   (__attribute__((address_space(3))) void*)lp,
                                   16, 0, 0);
}

// ---------------------------------------------------------------------------
// Generic 128x128x(K) GEMM: C[M,NOUT] = act(A[M,K] @ W[NOUT,K]^T + bias)
// AMODE: 0 = A is bf16 (global_load_lds staging), 1 = A is fp32 (manual stage+convert)
// EPI:   0 = fp32 out, no bias/act (store guarded by row<M)
//        1 = bf16 out, bias+ReLU   2 = bf16 out, bias+GELU  3 = bf16 out, bias only
//        4 = edge layer-1 epilogue: cols<256 -> h1b (bias+projS+projT, ReLU),
//            cols>=256 -> h1v (bias2+projS, GELU)
// grid: (NOUT/128, ceil(M/128))
// ---------------------------------------------------------------------------
template <int AMODE, int EPI>
__global__ __launch_bounds__(256) void gemm_k(
    const void* __restrict__ Av, const bf16_t* __restrict__ W,
    const float* __restrict__ bias, void* __restrict__ Cv,
    int M, int K, int NOUT,
    const int* __restrict__ src32, const int* __restrict__ dst32,
    const float* __restrict__ projS, const float* __restrict__ projT,
    const float* __restrict__ bias2, bf16_t* __restrict__ C2) {
  __shared__ __align__(16) unsigned short As[128 * 32];
  __shared__ __align__(16) unsigned short Bs[128 * 32];
  const int tid = threadIdx.x;
  const int lane = tid & 63;
  const int wave = tid >> 6;
  const int wm = wave & 1, wn = wave >> 1;
  const int fr = lane & 15, kg = lane >> 4;
  const int rowBase = blockIdx.y * 128;
  const int colBase = blockIdx.x * 128;

  f32x4 acc[4][4] = {};

  const int nK = K >> 5;
  for (int kt = 0; kt < nK; ++kt) {
    const int k0 = kt << 5;
    if (kt) __syncthreads();
    if constexpr (AMODE == 0) {
      const bf16_t* A = (const bf16_t*)Av;
#pragma unroll
      for (int c = 0; c < 2; ++c) {
        int r = wave * 32 + c * 16 + (lane >> 2);
        int gr = rowBase + r;
        gr = (gr < M) ? gr : (M - 1);
        async_cp16(A + (size_t)gr * K + k0 + (lane & 3) * 8,
                   &As[(wave * 32 + c * 16) * 32]);
        int wr = colBase + wave * 32 + c * 16 + (lane >> 2);
        async_cp16(W + (size_t)wr * K + k0 + (lane & 3) * 8,
                   &Bs[(wave * 32 + c * 16) * 32]);
      }
    } else {
      const float* A = (const float*)Av;
      int r = tid >> 1, hh = tid & 1;
      int gr = rowBase + r;
      gr = (gr < M) ? gr : (M - 1);
      const float4* gp = (const float4*)(A + (size_t)gr * K + k0 + hh * 16);
      float4 x0 = gp[0], x1 = gp[1], x2 = gp[2], x3 = gp[3];
      u16x8 p0 = {f2b(x0.x), f2b(x0.y), f2b(x0.z), f2b(x0.w),
                  f2b(x1.x), f2b(x1.y), f2b(x1.z), f2b(x1.w)};
      u16x8 p1 = {f2b(x2.x), f2b(x2.y), f2b(x2.z), f2b(x2.w),
                  f2b(x3.x), f2b(x3.y), f2b(x3.z), f2b(x3.w)};
      *(u16x8*)&As[r * 32 + hh * 16] = p0;
      *(u16x8*)&As[r * 32 + hh * 16 + 8] = p1;
      const u16x8* wp = (const u16x8*)(W + (size_t)(colBase + r) * K + k0 + hh * 16);
      *(u16x8*)&Bs[r * 32 + hh * 16] = wp[0];
      *(u16x8*)&Bs[r * 32 + hh * 16 + 8] = wp[1];
    }
    __syncthreads();
    bf16x8 af[4], bw[4];
#pragma unroll
    for (int i = 0; i < 4; ++i)
      af[i] = *(const bf16x8*)&As[(wm * 64 + i * 16 + fr) * 32 + kg * 8];
#pragma unroll
    for (int i = 0; i < 4; ++i)
      bw[i] = *(const bf16x8*)&Bs[(wn * 64 + i * 16 + fr) * 32 + kg * 8];
#pragma unroll
    for (int mi = 0; mi < 4; ++mi)
#pragma unroll
      for (int ni = 0; ni < 4; ++ni)
        acc[mi][ni] = __builtin_amdgcn_mfma_f32_16x16x32_bf16(
            af[mi], bw[ni], acc[mi][ni], 0, 0, 0);
  }

  const int r0 = rowBase + wm * 64;
  const int c0 = colBase + wn * 64;
  if constexpr (EPI == 0) {
    float* C = (float*)Cv;
#pragma unroll
    for (int mi = 0; mi < 4; ++mi)
#pragma unroll
      for (int reg = 0; reg < 4; ++reg) {
        int row = r0 + mi * 16 + kg * 4 + reg;
        if (row < M) {
#pragma unroll
          for (int ni = 0; ni < 4; ++ni) {
            int col = c0 + ni * 16 + fr;
            C[(size_t)row * NOUT + col] = acc[mi][ni][reg];
          }
        }
      }
  } else if constexpr (EPI == 4) {
    bf16_t* C = (bf16_t*)Cv;
#pragma unroll
    for (int mi = 0; mi < 4; ++mi)
#pragma unroll
      for (int reg = 0; reg < 4; ++reg) {
        int e = r0 + mi * 16 + kg * 4 + reg;
        int si = src32[e], di = dst32[e];
#pragma unroll
        for (int ni = 0; ni < 4; ++ni) {
          int col = c0 + ni * 16 + fr;
          float v = acc[mi][ni][reg];
          if (col < 256) {
            v += bias[col] + projS[(size_t)si * 512 + col] + projT[(size_t)di * 256 + col];
            v = fmaxf(v, 0.f);
            C[(size_t)e * 256 + col] = (bf16_t)v;
          } else {
            int c2 = col - 256;
            v += bias2[c2] + projS[(size_t)si * 512 + col];
            v = gelu_f(v);
            C2[(size_t)e * 256 + c2] = (bf16_t)v;
          }
        }
      }
  } else {
    bf16_t* C = (bf16_t*)Cv;
#pragma unroll
    for (int mi = 0; mi < 4; ++mi)
#pragma unroll
      for (int reg = 0; reg < 4; ++reg) {
        int row = r0 + mi * 16 + kg * 4 + reg;
#pragma unroll
        for (int ni = 0; ni < 4; ++ni) {
          int col = c0 + ni * 16 + fr;
          float v = acc[mi][ni][reg] + bias[col];
          if constexpr (EPI == 1) v = fmaxf(v, 0.f);
          if constexpr (EPI == 2) v = gelu_f(v);
          C[(size_t)row * NOUT + col] = (bf16_t)v;
        }
      }
  }
}

// logits[E,8] = (h2b[E,256] @ Wb3p[16,256]^T + bb3) / sqrt(32); one wave = 16 edges
__global__ __launch_bounds__(256) void logits_k(const bf16_t* __restrict__ h2b,
                                                const bf16_t* __restrict__ Wb3p,
                                                const float* __restrict__ bb3,
                                                float* __restrict__ logits) {
  const int lane = threadIdx.x & 63, wave = threadIdx.x >> 6;
  const int fr = lane & 15, kg = lane >> 4;
  const int e0 = blockIdx.x * 64 + wave * 16;
  f32x4 acc = {};
#pragma unroll
  for (int kt = 0; kt < 8; ++kt) {
    bf16x8 a = *(const bf16x8*)&h2b[(size_t)(e0 + fr) * 256 + kt * 32 + kg * 8];
    bf16x8 b = *(const bf16x8*)&Wb3p[(size_t)fr * 256 + kt * 32 + kg * 8];
    acc = __builtin_amdgcn_mfma_f32_16x16x32_bf16(a, b, acc, 0, 0, 0);
  }
  if (fr < 8) {
#pragma unroll
    for (int reg = 0; reg < 4; ++reg) {
      int e = e0 + kg * 4 + reg;
      logits[(size_t)e * 8 + fr] = (acc[reg] + bb3[fr]) * 0.17677669529663687f;
    }
  }
}

__global__ void detect_k(const int* __restrict__ ei, int* __restrict__ flag) {
  int v = ei[2 * threadIdx.x + 1];
  unsigned long long nz = __ballot(v != 0);
  if (threadIdx.x == 0) *flag = (nz != 0ULL) ? 1 : 0;  // 1 => int32 data
}

__global__ __launch_bounds__(256) void norm_k(const int* __restrict__ ei,
                                              const int* __restrict__ flag,
                                              int* __restrict__ dst32,
                                              int* __restrict__ src32) {
  int e = blockIdx.x * 256 + threadIdx.x;
  if (e >= EN) return;
  if (*flag) {
    dst32[e] = ei[e];
    src32[e] = ei[EN + e];
  } else {
    dst32[e] = ei[2 * e];
    src32[e] = ei[2 * EN + 2 * e];
  }
}

__global__ __launch_bounds__(256) void zero_k(unsigned int* __restrict__ p, int n) {
  int i = blockIdx.x * 256 + threadIdx.x;
  if (i < n) p[i] = 0u;
}

// dst[r*256+c] = (bf16)src[r*srcld + srcoff + c], cols fixed at 256, grid = rows
__global__ __launch_bounds__(256) void convw(const float* __restrict__ src,
                                             bf16_t* __restrict__ dst, int rows,
                                             int srcld, int srcoff) {
  int i = blockIdx.x * 256 + threadIdx.x;
  if (i >= rows * 256) return;
  int r = i >> 8, c = i & 255;
  dst[i] = (bf16_t)src[(size_t)r * srcld + srcoff + c];
}

__global__ __launch_bounds__(256) void hist_k(const int* __restrict__ dst32,
                                              int* __restrict__ counts) {
  int e = blockIdx.x * 256 + threadIdx.x;
  if (e < EN) atomicAdd(&counts[dst32[e]], 1);
}

__global__ __launch_bounds__(1024) void scan_k(const int* __restrict__ counts,
                                               int* __restrict__ offsets) {
  __shared__ int part[1024];
  const int t = threadIdx.x;
  const int base = t * 10;
  int s = 0;
#pragma unroll
  for (int j = 0; j < 10; ++j) {
    int i = base + j;
    if (i < NN) s += counts[i];
  }
  part[t] = s;
  __syncthreads();
  for (int off = 1; off < 1024; off <<= 1) {
    int v = (t >= off) ? part[t - off] : 0;
    __syncthreads();
    part[t] += v;
    __syncthreads();
  }
  int run = (t > 0) ? part[t - 1] : 0;
  for (int j = 0; j < 10; ++j) {
    int i = base + j;
    if (i < NN) {
      offsets[i] = run;
      run += counts[i];
    }
  }
  if (t == 0) offsets[NN] = part[1023];
}

__global__ __launch_bounds__(256) void scatter_k(const int* __restrict__ dst32,
                                                 const int* __restrict__ offsets,
                                                 int* __restrict__ cursor,
                                                 int* __restrict__ sorted) {
  int e = blockIdx.x * 256 + threadIdx.x;
  if (e >= EN) return;
  int d = dst32[e];
  int p = offsets[d] + atomicAdd(&cursor[d], 1);
  sorted[p] = e;
}

// one block per node; 8 half-wave groups (one per head), 32 lanes = head dims
__global__ __launch_bounds__(256) void agg_k(const float* __restrict__ logits,
                                             const bf16_t* __restrict__ V,
                                             const int* __restrict__ offsets,
                                             const int* __restrict__ sorted,
                                             bf16_t* __restrict__ aggb) {
  const int node = blockIdx.x;
  const int t = threadIdx.x, g = t >> 5, l = t & 31;
  const int beg = offsets[node], end = offsets[node + 1];
  float m = -1e30f;
  for (int i = beg + l; i < end; i += 32)
    m = fmaxf(m, logits[(size_t)sorted[i] * 8 + g]);
#pragma unroll
  for (int off = 16; off >= 1; off >>= 1) m = fmaxf(m, __shfl_xor(m, off, 64));
  float den = 0.f;
  for (int i = beg + l; i < end; i += 32)
    den += expf(logits[(size_t)sorted[i] * 8 + g] - m);
#pragma unroll
  for (int off = 16; off >= 1; off >>= 1) den += __shfl_xor(den, off, 64);
  float acc = 0.f;
  for (int i = beg; i < end; ++i) {
    int e = sorted[i];
    float ex = expf(logits[(size_t)e * 8 + g] - m);
    acc += ex * (float)V[(size_t)e * 256 + g * 32 + l];
  }
  float r = (den > 0.f) ? acc / den : 0.f;
  aggb[(size_t)node * 256 + g * 32 + l] = (bf16_t)r;
}

extern "C" void kernel_launch(void* const* d_in, const int* in_sizes, int n_in,
                              void* d_out, int out_size, void* d_ws, size_t ws_size,
                              hipStream_t stream) {
  const float* src_na = (const float*)d_in[0];
  const float* dst_na = (const float*)d_in[1];
  const float* ea = (const float*)d_in[2];
  const int* ei_raw = (const int*)d_in[3];
  const float* Wv1 = (const float*)d_in[4];
  const float* bv1 = (const float*)d_in[5];
  const float* Wv2 = (const float*)d_in[6];
  const float* bv2 = (const float*)d_in[7];
  const float* Wv3 = (const float*)d_in[8];
  const float* bv3 = (const float*)d_in[9];
  const float* Wb1 = (const float*)d_in[10];
  const float* bb1 = (const float*)d_in[11];
  const float* Wb2 = (const float*)d_in[12];
  const float* bb2 = (const float*)d_in[13];
  const float* Wb3 = (const float*)d_in[14];
  const float* bb3 = (const float*)d_in[15];
  const float* WO = (const float*)d_in[16];

  char* base = (char*)d_ws;
  size_t off = 0;
  auto alloc = [&](size_t bytes) -> void* {
    void* p = base + off;
    off += (bytes + 255) & ~(size_t)255;
    return p;
  };
  bf16_t* Wsrc = (bf16_t*)alloc(512 * 256 * 2);  // [bias-src | value-src] proj weights
  bf16_t* Wdst = (bf16_t*)alloc(256 * 256 * 2);
  bf16_t* Wea = (bf16_t*)alloc(512 * 256 * 2);   // [bias-ea | value-ea]
  bf16_t* Wb2c = (bf16_t*)alloc(256 * 256 * 2);
  bf16_t* Wv2c = (bf16_t*)alloc(256 * 256 * 2);
  bf16_t* Wv3c = (bf16_t*)alloc(256 * 256 * 2);
  bf16_t* WOc = (bf16_t*)alloc(256 * 256 * 2);
  bf16_t* Wb3p = (bf16_t*)alloc(16 * 256 * 2);   // Wb3 padded to 16 rows
  float* projS = (float*)alloc((size_t)NN * 512 * 4);  // [bprojS | vprojS]
  float* projT = (float*)alloc((size_t)NN * 256 * 4);
  bf16_t* bufA = (bf16_t*)alloc((size_t)EN * 256 * 2);  // h1b -> h2v
  bf16_t* bufB = (bf16_t*)alloc((size_t)EN * 256 * 2);  // h1v -> V
  bf16_t* bufC = (bf16_t*)alloc((size_t)EN * 256 * 2);  // h2b
  float* logits = (float*)alloc((size_t)EN * 8 * 4);
  bf16_t* aggb = (bf16_t*)alloc((size_t)NN * 256 * 2);
  int* counts = (int*)alloc(NN * 4);
  int* cursor = (int*)alloc(NN * 4);
  int* offsets = (int*)alloc((NN + 1) * 4);
  int* sorted = (int*)alloc(EN * 4);
  int* dst32 = (int*)alloc(EN * 4);
  int* src32 = (int*)alloc(EN * 4);
  int* flag = (int*)alloc(4);
  if (off > ws_size) return;  // workspace insufficient -> fail loudly via validation

  // weight prep
  zero_k<<<dim3(8), 256, 0, stream>>>((unsigned int*)Wb3p, 16 * 256 * 2 / 4);
  convw<<<dim3(256), 256, 0, stream>>>(Wb1, Wsrc, 256, 768, 0);
  convw<<<dim3(256), 256, 0, stream>>>(Wv1, Wsrc + 256 * 256, 256, 512, 0);
  convw<<<dim3(256), 256, 0, stream>>>(Wb1, Wdst, 256, 768, 512);
  convw<<<dim3(256), 256, 0, stream>>>(Wb1, Wea, 256, 768, 256);
  convw<<<dim3(256), 256, 0, stream>>>(Wv1, Wea + 256 * 256, 256, 512, 256);
  convw<<<dim3(256), 256, 0, stream>>>(Wb2, Wb2c, 256, 256, 0);
  convw<<<dim3(256), 256, 0, stream>>>(Wv2, Wv2c, 256, 256, 0);
  convw<<<dim3(256), 256, 0, stream>>>(Wv3, Wv3c, 256, 256, 0);
  convw<<<dim3(256), 256, 0, stream>>>(WO, WOc, 256, 256, 0);
  convw<<<dim3(8), 256, 0, stream>>>(Wb3, Wb3p, 8, 256, 0);

  // edge index normalization (int64-vs-int32 robust)
  detect_k<<<1, 64, 0, stream>>>(ei_raw, flag);
  norm_k<<<1250, 256, 0, stream>>>(ei_raw, flag, dst32, src32);
  zero_k<<<dim3((NN + 255) / 256), 256, 0, stream>>>((unsigned int*)counts, NN);
  zero_k<<<dim3((NN + 255) / 256), 256, 0, stream>>>((unsigned int*)cursor, NN);

  // node projections: projS[N,512] = src_na @ [Wb1s|Wv1s]^T ; projT[N,256] = dst_na @ Wb1t^T
  gemm_k<1, 0><<<dim3(4, 79), 256, 0, stream>>>(src_na, Wsrc, nullptr, projS, NN, 256, 512,
                                                nullptr, nullptr, nullptr, nullptr, nullptr, nullptr);
  gemm_k<1, 0><<<dim3(2, 79), 256, 0, stream>>>(dst_na, Wdst, nullptr, projT, NN, 256, 256,
                                                nullptr, nullptr, nullptr, nullptr, nullptr, nullptr);
  // edge layer 1 (fused bias+value): h1b=bufA, h1v=bufB
  gemm_k<1, 4><<<dim3(4, 2500), 256, 0, stream>>>(ea, Wea, bb1, bufA, EN, 256, 512,
                                                  src32, dst32, projS, projT, bv1, bufB);
  // bias layer 2: h2b = relu(h1b@Wb2^T+bb2) -> bufC
  gemm_k<0, 1><<<dim3(2, 2500), 256, 0, stream>>>(bufA, Wb2c, bb2, bufC, EN, 256, 256,
                                                  nullptr, nullptr, nullptr, nullptr, nullptr, nullptr);
  // bias layer 3 -> logits
  logits_k<<<5000, 256, 0, stream>>>(bufC, Wb3p, bb3, logits);
  // value layer 2: h2v = gelu(h1v@Wv2^T+bv2) -> bufA
  gemm_k<0, 2><<<dim3(2, 2500), 256, 0, stream>>>(bufB, Wv2c, bv2, bufA, EN, 256, 256,
                                                  nullptr, nullptr, nullptr, nullptr, nullptr, nullptr);
  // value layer 3: V = h2v@Wv3^T+bv3 -> bufB
  gemm_k<0, 3><<<dim3(2, 2500), 256, 0, stream>>>(bufA, Wv3c, bv3, bufB, EN, 256, 256,
                                                  nullptr, nullptr, nullptr, nullptr, nullptr, nullptr);

  // counting sort by destination node
  hist_k<<<1250, 256, 0, stream>>>(dst32, counts);
  scan_k<<<1, 1024, 0, stream>>>(counts, offsets);
  scatter_k<<<1250, 256, 0, stream>>>(dst32, offsets, cursor, sorted);

  // per-node softmax + weighted aggregation
  agg_k<<<NN, 256, 0, stream>>>(logits, bufB, offsets, sorted, aggb);

  // out = agg @ WO^T (fp32 out)
  gemm_k<0, 0><<<dim3(2, 79), 256, 0, stream>>>(aggb, WOc, nullptr, d_out, NN, 256, 256,
                                                nullptr, nullptr, nullptr, nullptr, nullptr, nullptr);
}

// Round 2
// 1314.826 us; speedup vs baseline: 1.1979x; 1.1979x over previous
//
#include <hip/hip_runtime.h>
#include <hip/hip_bf16.h>
#include <cstdint>
#include <cstddef>

#define EN 320000
#define NN 10000

typedef __bf16 bf16_t;
typedef __bf16 bf16x8 __attribute__((ext_vector_type(8)));
typedef float f32x4 __attribute__((ext_vector_type(4)));
typedef unsigned short u16x8 __attribute__((ext_vector_type(8)));

__device__ __forceinline__ unsigned short f2b(float x) {
  bf16_t h = (bf16_t)x;
  return __builtin_bit_cast(unsigned short, h);
}
__device__ __forceinline__ float gelu_f(float x) {
  return 0.5f * x * (1.0f + erff(x * 0.70710678118654752f));
}
__device__ __forceinline__ void async_cp16(const void* gp, void* lp) {
  __builtin_amdgcn_global_load_lds((__attribute__((address_space(1))) void*)gp,
                                   (__attribute__((address_space(3))) void*)lp,
                                   16, 0, 0);
}

// ---------------------------------------------------------------------------
// LDS layouts (all 16B chunks, XOR-swizzled so b128 fragment reads hit all 8
// bank-granules evenly; 2-lane aliasing is free per m136):
//   A-panel  [64 rows x 256 k] bf16: chunk(row,kc) at  row*32 + (kc ^ (row&7))
//   B-tile   [128 col x 32 k]  bf16: chunk(col,kg) at  col*4  + (kg ^ ((col>>2)&3))
// ---------------------------------------------------------------------------
__device__ __forceinline__ bf16x8 read_a(const unsigned short* P, int row, int kc) {
  return *(const bf16x8*)&P[(row * 32 + (kc ^ (row & 7))) * 8];
}
__device__ __forceinline__ bf16x8 read_b(const unsigned short* P, int col, int kg) {
  return *(const bf16x8*)&P[(col * 4 + (kg ^ ((col >> 2) & 3))) * 8];
}
__device__ __forceinline__ void stage_b_tile(const bf16_t* W, int cc, int kt,
                                             unsigned short* buf, int wave, int lane) {
#pragma unroll
  for (int c = 0; c < 2; ++c) {
    int n0 = wave * 128 + c * 64;
    int nl = n0 + lane;
    int col = nl >> 2;
    int kgq = (nl & 3) ^ ((col >> 2) & 3);
    async_cp16(W + (size_t)(cc * 128 + col) * 256 + kt * 32 + kgq * 8, &buf[n0 * 8]);
  }
}
// A-panel layout staging of a 16x256 bf16 matrix (Wb3p) for read_a(fr,kc) use
__device__ __forceinline__ void stage_wb3(const bf16_t* Wp, unsigned short* buf,
                                          int wave, int lane) {
#pragma unroll
  for (int c = 0; c < 2; ++c) {
    int n0 = wave * 128 + c * 64;
    int nl = n0 + lane;
    int h = nl >> 5, p = nl & 31;
    int kc = p ^ (h & 7);
    async_cp16(Wp + (size_t)h * 256 + kc * 8, &buf[n0 * 8]);
  }
}
// stage A-panel from bf16 global [M,256]
__device__ __forceinline__ void stage_a_bf16(const bf16_t* A, unsigned short* As,
                                             int rowBase, int M, int wave, int lane) {
  int sub = lane >> 5, p = lane & 31;
#pragma unroll
  for (int j = 0; j < 8; ++j) {
    int row = wave * 16 + j * 2 + sub;
    int gr = rowBase + row;
    gr = (gr < M) ? gr : (M - 1);
    int kc = p ^ (row & 7);
    async_cp16(A + (size_t)gr * 256 + kc * 8, &As[(wave * 16 + j * 2) * 32 * 8]);
  }
}

// ---------------------------------------------------------------------------
// A-resident GEMM: block = 64 rows x NOUT(=NCC*128) cols, K=256.
// AMODE 0: A bf16 (async). AMODE 1: A fp32 (manual convert staging).
// EPI 0: fp32 out, row<M guard. EPI 4: edge layer-1 (h1b relu + h1v gelu, gathers).
// ---------------------------------------------------------------------------
template <int AMODE, int EPI, int NCC>
__global__ __launch_bounds__(256) void gemm2(
    const void* __restrict__ Av, const bf16_t* __restrict__ W,
    const float* __restrict__ bias, void* __restrict__ Cv, int M,
    const int* __restrict__ src32, const int* __restrict__ dst32,
    const float* __restrict__ projS, const float* __restrict__ projT,
    const float* __restrict__ bias2, bf16_t* __restrict__ C2) {
  __shared__ __align__(16) unsigned short As[2048 * 8];  // 32 KB
  __shared__ __align__(16) unsigned short Bs[2][512 * 8]; // 2 x 8 KB
  const int tid = threadIdx.x;
  const int lane = tid & 63, wave = tid >> 6;
  const int wm = wave & 1, wn = wave >> 1;
  const int fr = lane & 15, kg = lane >> 4;
  const int rowBase = blockIdx.x * 64;

  if constexpr (AMODE == 0) {
    stage_a_bf16((const bf16_t*)Av, As, rowBase, M, wave, lane);
  } else {
    const float* A = (const float*)Av;
    int row = tid >> 2, qq = tid & 3;
    int gr = rowBase + row;
    gr = (gr < M) ? gr : (M - 1);
    const float4* gp = (const float4*)(A + (size_t)gr * 256 + qq * 64);
#pragma unroll
    for (int q = 0; q < 2; ++q) {
      float4 y[8];
#pragma unroll
      for (int u = 0; u < 8; ++u) y[u] = gp[q * 8 + u];
#pragma unroll
      for (int c = 0; c < 4; ++c) {
        int kc = qq * 8 + q * 4 + c;
        u16x8 pk = {f2b(y[2 * c].x), f2b(y[2 * c].y), f2b(y[2 * c].z), f2b(y[2 * c].w),
                    f2b(y[2 * c + 1].x), f2b(y[2 * c + 1].y), f2b(y[2 * c + 1].z),
                    f2b(y[2 * c + 1].w)};
        *(u16x8*)&As[(row * 32 + (kc ^ (row & 7))) * 8] = pk;
      }
    }
  }
  stage_b_tile(W, 0, 0, Bs[0], wave, lane);
  __syncthreads();

  const int T = NCC * 8;
  for (int cc = 0; cc < NCC; ++cc) {
    f32x4 acc[2][4] = {};
    for (int kt = 0; kt < 8; ++kt) {
      int j = cc * 8 + kt;
      if (j + 1 < T) stage_b_tile(W, (j + 1) >> 3, (j + 1) & 7, Bs[(j + 1) & 1], wave, lane);
      const unsigned short* B = Bs[j & 1];
      bf16x8 af[2], bw[4];
#pragma unroll
      for (int mi = 0; mi < 2; ++mi) af[mi] = read_a(As, wm * 32 + mi * 16 + fr, kt * 4 + kg);
#pragma unroll
      for (int ni = 0; ni < 4; ++ni) bw[ni] = read_b(B, wn * 64 + ni * 16 + fr, kg);
#pragma unroll
      for (int mi = 0; mi < 2; ++mi)
#pragma unroll
        for (int ni = 0; ni < 4; ++ni)
          acc[mi][ni] = __builtin_amdgcn_mfma_f32_16x16x32_bf16(af[mi], bw[ni], acc[mi][ni], 0, 0, 0);
      __syncthreads();
    }
    if constexpr (EPI == 0) {
      float* C = (float*)Cv;
#pragma unroll
      for (int mi = 0; mi < 2; ++mi)
#pragma unroll
        for (int reg = 0; reg < 4; ++reg) {
          int row = rowBase + wm * 32 + mi * 16 + kg * 4 + reg;
          if (row < M) {
#pragma unroll
            for (int ni = 0; ni < 4; ++ni)
              C[(size_t)row * (NCC * 128) + cc * 128 + wn * 64 + ni * 16 + fr] = acc[mi][ni][reg];
          }
        }
    } else {  // EPI == 4
      bf16_t* C = (bf16_t*)Cv;
#pragma unroll
      for (int mi = 0; mi < 2; ++mi)
#pragma unroll
        for (int reg = 0; reg < 4; ++reg) {
          int e = rowBase + wm * 32 + mi * 16 + kg * 4 + reg;
          int si = src32[e], di = dst32[e];
#pragma unroll
          for (int ni = 0; ni < 4; ++ni) {
            int col = cc * 128 + wn * 64 + ni * 16 + fr;
            float v = acc[mi][ni][reg];
            if (col < 256) {
              v += bias[col] + projS[(size_t)si * 512 + col] + projT[(size_t)di * 256 + col];
              v = fmaxf(v, 0.f);
              C[(size_t)e * 256 + col] = (bf16_t)v;
            } else {
              int c2 = col - 256;
              v += bias2[c2] + projS[(size_t)si * 512 + col];
              v = gelu_f(v);
              C2[(size_t)e * 256 + c2] = (bf16_t)v;
            }
          }
        }
    }
  }
}

// bias path: h2b = relu(h1b@Wb2^T+bb2) kept in LDS; logits = (h2b@Wb3^T+bb3)/sqrt(d)
__global__ __launch_bounds__(256) void bias_fuse(
    const bf16_t* __restrict__ h1b, const bf16_t* __restrict__ Wb2c,
    const float* __restrict__ bb2, const bf16_t* __restrict__ Wb3p,
    const float* __restrict__ bb3, float* __restrict__ logits) {
  __shared__ __align__(16) unsigned short As[2048 * 8];
  __shared__ __align__(16) unsigned short Bs[2][512 * 8];
  const int tid = threadIdx.x;
  const int lane = tid & 63, wave = tid >> 6;
  const int wm = wave & 1, wn = wave >> 1;
  const int fr = lane & 15, kg = lane >> 4;
  const int rowBase = blockIdx.x * 64;

  stage_a_bf16(h1b, As, rowBase, EN, wave, lane);
  stage_b_tile(Wb2c, 0, 0, Bs[0], wave, lane);
  __syncthreads();

  f32x4 acc[2][2][4] = {};
  for (int cc = 0; cc < 2; ++cc)
    for (int kt = 0; kt < 8; ++kt) {
      int j = cc * 8 + kt;
      if (j + 1 < 16)
        stage_b_tile(Wb2c, (j + 1) >> 3, (j + 1) & 7, Bs[(j + 1) & 1], wave, lane);
      else
        stage_wb3(Wb3p, Bs[0], wave, lane);  // prefetch phase-2 weights
      const unsigned short* B = Bs[j & 1];
      bf16x8 af[2], bw[4];
#pragma unroll
      for (int mi = 0; mi < 2; ++mi) af[mi] = read_a(As, wm * 32 + mi * 16 + fr, kt * 4 + kg);
#pragma unroll
      for (int ni = 0; ni < 4; ++ni) bw[ni] = read_b(B, wn * 64 + ni * 16 + fr, kg);
#pragma unroll
      for (int mi = 0; mi < 2; ++mi)
#pragma unroll
        for (int ni = 0; ni < 4; ++ni)
          acc[cc][mi][ni] = __builtin_amdgcn_mfma_f32_16x16x32_bf16(af[mi], bw[ni], acc[cc][mi][ni], 0, 0, 0);
      __syncthreads();
    }
  // overwrite A-panel with h2b (bf16, A-layout)
#pragma unroll
  for (int cc = 0; cc < 2; ++cc)
#pragma unroll
    for (int mi = 0; mi < 2; ++mi)
#pragma unroll
      for (int reg = 0; reg < 4; ++reg) {
        int row = wm * 32 + mi * 16 + kg * 4 + reg;
#pragma unroll
        for (int ni = 0; ni < 4; ++ni) {
          int col = cc * 128 + wn * 64 + ni * 16 + fr;
          float v = fmaxf(acc[cc][mi][ni][reg] + bb2[col], 0.f);
          As[(row * 32 + ((col >> 3) ^ (row & 7))) * 8 + (col & 7)] = f2b(v);
        }
      }
  __syncthreads();
  // logits: one 16-edge MFMA group per wave
  f32x4 la = {};
#pragma unroll
  for (int kt = 0; kt < 8; ++kt) {
    int kc = kt * 4 + kg;
    bf16x8 a = read_a(As, wave * 16 + fr, kc);
    bf16x8 b = read_a(Bs[0], fr, kc);
    la = __builtin_amdgcn_mfma_f32_16x16x32_bf16(a, b, la, 0, 0, 0);
  }
  if (fr < 8) {
#pragma unroll
    for (int reg = 0; reg < 4; ++reg) {
      int e = rowBase + wave * 16 + kg * 4 + reg;
      logits[(size_t)e * 8 + fr] = (la[reg] + bb3[fr]) * 0.17677669529663687f;
    }
  }
}

// value path: h2v = gelu(h1v@Wv2^T+bv2) in LDS; V = h2v@Wv3^T+bv3
__global__ __launch_bounds__(256) void val_fuse(
    const bf16_t* __restrict__ h1v, const bf16_t* __restrict__ Wv2c,
    const float* __restrict__ bv2, const bf16_t* __restrict__ Wv3c,
    const float* __restrict__ bv3, bf16_t* __restrict__ V) {
  __shared__ __align__(16) unsigned short As[2048 * 8];
  __shared__ __align__(16) unsigned short Bs[2][512 * 8];
  const int tid = threadIdx.x;
  const int lane = tid & 63, wave = tid >> 6;
  const int wm = wave & 1, wn = wave >> 1;
  const int fr = lane & 15, kg = lane >> 4;
  const int rowBase = blockIdx.x * 64;

  stage_a_bf16(h1v, As, rowBase, EN, wave, lane);
  stage_b_tile(Wv2c, 0, 0, Bs[0], wave, lane);
  __syncthreads();

  f32x4 acc[2][2][4] = {};
  for (int cc = 0; cc < 2; ++cc)
    for (int kt = 0; kt < 8; ++kt) {
      int j = cc * 8 + kt;
      if (j + 1 < 16)
        stage_b_tile(Wv2c, (j + 1) >> 3, (j + 1) & 7, Bs[(j + 1) & 1], wave, lane);
      else
        stage_b_tile(Wv3c, 0, 0, Bs[0], wave, lane);  // prefetch phase-2 first tile
      const unsigned short* B = Bs[j & 1];
      bf16x8 af[2], bw[4];
#pragma unroll
      for (int mi = 0; mi < 2; ++mi) af[mi] = read_a(As, wm * 32 + mi * 16 + fr, kt * 4 + kg);
#pragma unroll
      for (int ni = 0; ni < 4; ++ni) bw[ni] = read_b(B, wn * 64 + ni * 16 + fr, kg);
#pragma unroll
      for (int mi = 0; mi < 2; ++mi)
#pragma unroll
        for (int ni = 0; ni < 4; ++ni)
          acc[cc][mi][ni] = __builtin_amdgcn_mfma_f32_16x16x32_bf16(af[mi], bw[ni], acc[cc][mi][ni], 0, 0, 0);
      __syncthreads();
    }
#pragma unroll
  for (int cc = 0; cc < 2; ++cc)
#pragma unroll
    for (int mi = 0; mi < 2; ++mi)
#pragma unroll
      for (int reg = 0; reg < 4; ++reg) {
        int row = wm * 32 + mi * 16 + kg * 4 + reg;
#pragma unroll
        for (int ni = 0; ni < 4; ++ni) {
          int col = cc * 128 + wn * 64 + ni * 16 + fr;
          float v = gelu_f(acc[cc][mi][ni][reg] + bv2[col]);
          As[(row * 32 + ((col >> 3) ^ (row & 7))) * 8 + (col & 7)] = f2b(v);
        }
      }
  __syncthreads();
  // phase 2: V = h2v @ Wv3^T + bv3
  for (int cc2 = 0; cc2 < 2; ++cc2) {
    f32x4 a2[2][4] = {};
    for (int kt = 0; kt < 8; ++kt) {
      int j2 = cc2 * 8 + kt;
      if (j2 + 1 < 16)
        stage_b_tile(Wv3c, (j2 + 1) >> 3, (j2 + 1) & 7, Bs[(j2 + 1) & 1], wave, lane);
      const unsigned short* B = Bs[j2 & 1];
      bf16x8 af[2], bw[4];
#pragma unroll
      for (int mi = 0; mi < 2; ++mi) af[mi] = read_a(As, wm * 32 + mi * 16 + fr, kt * 4 + kg);
#pragma unroll
      for (int ni = 0; ni < 4; ++ni) bw[ni] = read_b(B, wn * 64 + ni * 16 + fr, kg);
#pragma unroll
      for (int mi = 0; mi < 2; ++mi)
#pragma unroll
        for (int ni = 0; ni < 4; ++ni)
          a2[mi][ni] = __builtin_amdgcn_mfma_f32_16x16x32_bf16(af[mi], bw[ni], a2[mi][ni], 0, 0, 0);
      __syncthreads();
    }
#pragma unroll
    for (int mi = 0; mi < 2; ++mi)
#pragma unroll
      for (int reg = 0; reg < 4; ++reg) {
        int e = rowBase + wm * 32 + mi * 16 + kg * 4 + reg;
#pragma unroll
        for (int ni = 0; ni < 4; ++ni) {
          int col = cc2 * 128 + wn * 64 + ni * 16 + fr;
          V[(size_t)e * 256 + col] = (bf16_t)(a2[mi][ni][reg] + bv3[col]);
        }
      }
  }
}

// fused weight conversion + zero-init
__global__ __launch_bounds__(256) void prep_k(
    const float* __restrict__ Wb1, const float* __restrict__ Wv1,
    const float* __restrict__ Wb2, const float* __restrict__ Wv2,
    const float* __restrict__ Wv3, const float* __restrict__ WO,
    const float* __restrict__ Wb3, bf16_t* __restrict__ Wsrc,
    bf16_t* __restrict__ Wdst, bf16_t* __restrict__ Wea,
    bf16_t* __restrict__ Wb2c, bf16_t* __restrict__ Wv2c,
    bf16_t* __restrict__ Wv3c, bf16_t* __restrict__ WOc,
    bf16_t* __restrict__ Wb3p, int* __restrict__ counts, int* __restrict__ cursor) {
  int i = blockIdx.x * 256 + threadIdx.x;
  if (i < 589824) {
    int seg = i >> 16, j = i & 65535, r = j >> 8, c = j & 255;
    const float* src;
    bf16_t* dst;
    int ld, off;
    switch (seg) {
      case 0: src = Wb1; dst = Wsrc; ld = 768; off = 0; break;
      case 1: src = Wv1; dst = Wsrc + 65536; ld = 512; off = 0; break;
      case 2: src = Wb1; dst = Wdst; ld = 768; off = 512; break;
      case 3: src = Wb1; dst = Wea; ld = 768; off = 256; break;
      case 4: src = Wv1; dst = Wea + 65536; ld = 512; off = 256; break;
      case 5: src = Wb2; dst = Wb2c; ld = 256; off = 0; break;
      case 6: src = Wv2; dst = Wv2c; ld = 256; off = 0; break;
      case 7: src = Wv3; dst = Wv3c; ld = 256; off = 0; break;
      default: src = WO; dst = WOc; ld = 256; off = 0; break;
    }
    dst[j] = (bf16_t)src[(size_t)r * ld + off + c];
  } else if (i < 593920) {
    int j = i - 589824, r = j >> 8, c = j & 255;
    Wb3p[j] = (r < 8) ? (bf16_t)Wb3[r * 256 + c] : (bf16_t)0.f;
  } else if (i < 593920 + NN) {
    counts[i - 593920] = 0;
  } else if (i < 593920 + 2 * NN) {
    cursor[i - 593920 - NN] = 0;
  }
}

__global__ void detect_k(const int* __restrict__ ei, int* __restrict__ flag) {
  int v = ei[2 * threadIdx.x + 1];
  unsigned long long nz = __ballot(v != 0);
  if (threadIdx.x == 0) *flag = (nz != 0ULL) ? 1 : 0;  // 1 => int32 data
}

__global__ __launch_bounds__(256) void normhist_k(const int* __restrict__ ei,
                                                  const int* __restrict__ flag,
                                                  int* __restrict__ dst32,
                                                  int* __restrict__ src32,
                                                  int* __restrict__ counts) {
  int e = blockIdx.x * 256 + threadIdx.x;
  if (e >= EN) return;
  int d, s;
  if (*flag) { d = ei[e]; s = ei[EN + e]; }
  else { d = ei[2 * e]; s = ei[2 * EN + 2 * e]; }
  dst32[e] = d;
  src32[e] = s;
  atomicAdd(&counts[d], 1);
}

__global__ __launch_bounds__(1024) void scan_k(const int* __restrict__ counts,
                                               int* __restrict__ offsets) {
  __shared__ int part[1024];
  const int t = threadIdx.x;
  const int base = t * 10;
  int s = 0;
#pragma unroll
  for (int j = 0; j < 10; ++j) {
    int i = base + j;
    if (i < NN) s += counts[i];
  }
  part[t] = s;
  __syncthreads();
  for (int off = 1; off < 1024; off <<= 1) {
    int v = (t >= off) ? part[t - off] : 0;
    __syncthreads();
    part[t] += v;
    __syncthreads();
  }
  int run = (t > 0) ? part[t - 1] : 0;
  for (int j = 0; j < 10; ++j) {
    int i = base + j;
    if (i < NN) {
      offsets[i] = run;
      run += counts[i];
    }
  }
  if (t == 0) offsets[NN] = part[1023];
}

__global__ __launch_bounds__(256) void scatter_k(const int* __restrict__ dst32,
                                                 const int* __restrict__ offsets,
                                                 int* __restrict__ cursor,
                                                 int* __restrict__ sorted) {
  int e = blockIdx.x * 256 + threadIdx.x;
  if (e >= EN) return;
  int d = dst32[e];
  int p = offsets[d] + atomicAdd(&cursor[d], 1);
  sorted[p] = e;
}

// one block per node; 8 half-wave groups (one per head), 32 lanes = head dims
__global__ __launch_bounds__(256) void agg_k(const float* __restrict__ logits,
                                             const bf16_t* __restrict__ V,
                                             const int* __restrict__ offsets,
                                             const int* __restrict__ sorted,
                                             bf16_t* __restrict__ aggb) {
  const int node = blockIdx.x;
  const int t = threadIdx.x, g = t >> 5, l = t & 31;
  const int beg = offsets[node], end = offsets[node + 1];
  float m = -1e30f;
  for (int i = beg + l; i < end; i += 32)
    m = fmaxf(m, logits[(size_t)sorted[i] * 8 + g]);
#pragma unroll
  for (int off = 16; off >= 1; off >>= 1) m = fmaxf(m, __shfl_xor(m, off, 64));
  float den = 0.f;
  for (int i = beg + l; i < end; i += 32)
    den += expf(logits[(size_t)sorted[i] * 8 + g] - m);
#pragma unroll
  for (int off = 16; off >= 1; off >>= 1) den += __shfl_xor(den, off, 64);
  float acc = 0.f;
  for (int i = beg; i < end; ++i) {
    int e = sorted[i];
    float ex = expf(logits[(size_t)e * 8 + g] - m);
    acc += ex * (float)V[(size_t)e * 256 + g * 32 + l];
  }
  float r = (den > 0.f) ? acc / den : 0.f;
  aggb[(size_t)node * 256 + g * 32 + l] = (bf16_t)r;
}

extern "C" void kernel_launch(void* const* d_in, const int* in_sizes, int n_in,
                              void* d_out, int out_size, void* d_ws, size_t ws_size,
                              hipStream_t stream) {
  const float* src_na = (const float*)d_in[0];
  const float* dst_na = (const float*)d_in[1];
  const float* ea = (const float*)d_in[2];
  const int* ei_raw = (const int*)d_in[3];
  const float* Wv1 = (const float*)d_in[4];
  const float* bv1 = (const float*)d_in[5];
  const float* Wv2 = (const float*)d_in[6];
  const float* bv2 = (const float*)d_in[7];
  const float* Wv3 = (const float*)d_in[8];
  const float* bv3 = (const float*)d_in[9];
  const float* Wb1 = (const float*)d_in[10];
  const float* bb1 = (const float*)d_in[11];
  const float* Wb2 = (const float*)d_in[12];
  const float* bb2 = (const float*)d_in[13];
  const float* Wb3 = (const float*)d_in[14];
  const float* bb3 = (const float*)d_in[15];
  const float* WO = (const float*)d_in[16];

  char* base = (char*)d_ws;
  size_t off = 0;
  auto alloc = [&](size_t bytes) -> void* {
    void* p = base + off;
    off += (bytes + 255) & ~(size_t)255;
    return p;
  };
  bf16_t* Wsrc = (bf16_t*)alloc(512 * 256 * 2);
  bf16_t* Wdst = (bf16_t*)alloc(256 * 256 * 2);
  bf16_t* Wea = (bf16_t*)alloc(512 * 256 * 2);
  bf16_t* Wb2c = (bf16_t*)alloc(256 * 256 * 2);
  bf16_t* Wv2c = (bf16_t*)alloc(256 * 256 * 2);
  bf16_t* Wv3c = (bf16_t*)alloc(256 * 256 * 2);
  bf16_t* WOc = (bf16_t*)alloc(256 * 256 * 2);
  bf16_t* Wb3p = (bf16_t*)alloc(16 * 256 * 2);
  float* projS = (float*)alloc((size_t)NN * 512 * 4);
  float* projT = (float*)alloc((size_t)NN * 256 * 4);
  bf16_t* bufA = (bf16_t*)alloc((size_t)EN * 256 * 2);  // h1b
  bf16_t* bufB = (bf16_t*)alloc((size_t)EN * 256 * 2);  // h1v
  bf16_t* bufV = (bf16_t*)alloc((size_t)EN * 256 * 2);  // V
  float* logits = (float*)alloc((size_t)EN * 8 * 4);
  bf16_t* aggb = (bf16_t*)alloc((size_t)NN * 256 * 2);
  int* counts = (int*)alloc(NN * 4);
  int* cursor = (int*)alloc(NN * 4);
  int* offsets = (int*)alloc((NN + 1) * 4);
  int* sorted = (int*)alloc(EN * 4);
  int* dst32 = (int*)alloc(EN * 4);
  int* src32 = (int*)alloc(EN * 4);
  int* flag = (int*)alloc(4);
  if (off > ws_size) return;

  prep_k<<<2399, 256, 0, stream>>>(Wb1, Wv1, Wb2, Wv2, Wv3, WO, Wb3, Wsrc, Wdst, Wea,
                                   Wb2c, Wv2c, Wv3c, WOc, Wb3p, counts, cursor);
  detect_k<<<1, 64, 0, stream>>>(ei_raw, flag);
  normhist_k<<<1250, 256, 0, stream>>>(ei_raw, flag, dst32, src32, counts);
  scan_k<<<1, 1024, 0, stream>>>(counts, offsets);
  scatter_k<<<1250, 256, 0, stream>>>(dst32, offsets, cursor, sorted);

  // node projections
  gemm2<1, 0, 4><<<157, 256, 0, stream>>>(src_na, Wsrc, nullptr, projS, NN,
                                          nullptr, nullptr, nullptr, nullptr, nullptr, nullptr);
  gemm2<1, 0, 2><<<157, 256, 0, stream>>>(dst_na, Wdst, nullptr, projT, NN,
                                          nullptr, nullptr, nullptr, nullptr, nullptr, nullptr);
  // edge layer 1 (bias h1b + value h1v fused)
  gemm2<1, 4, 4><<<5000, 256, 0, stream>>>(ea, Wea, bb1, bufA, EN,
                                           src32, dst32, projS, projT, bv1, bufB);
  // bias layer 2+3 fused -> logits
  bias_fuse<<<5000, 256, 0, stream>>>(bufA, Wb2c, bb2, Wb3p, bb3, logits);
  // value layer 2+3 fused -> V
  val_fuse<<<5000, 256, 0, stream>>>(bufB, Wv2c, bv2, Wv3c, bv3, bufV);

  // per-node softmax + weighted aggregation
  agg_k<<<NN, 256, 0, stream>>>(logits, bufV, offsets, sorted, aggb);

  // out = agg @ WO^T (fp32)
  gemm2<0, 0, 2><<<157, 256, 0, stream>>>(aggb, WOc, nullptr, d_out, NN,
                                          nullptr, nullptr, nullptr, nullptr, nullptr, nullptr);
}